// Round 1
// baseline (3996.864 us; speedup 1.0000x reference)
//
#include <hip/hip_runtime.h>

#define N_VOX 50000
#define BATCH 2
#define DD 8
#define HH 160
#define WW 160
#define PD 10
#define PH 162
#define PW 162
#define KK 27
#define GRID_ELEMS (BATCH*PD*PH*PW)   // 524880
#define OUT_ELEMS (BATCH*128*DD*HH*WW) // 52,428,800

// ---------------- rulebook ----------------
__global__ void k_scatter_grid(const int* __restrict__ coors, int* __restrict__ grid) {
    int n = blockIdx.x * 256 + threadIdx.x;
    if (n >= N_VOX) return;
    int b = coors[n*4+0], z = coors[n*4+1], y = coors[n*4+2], x = coors[n*4+3];
    grid[((b*PD + z+1)*PH + (y+1))*PW + (x+1)] = n;
}

__global__ void k_build_nbr(const int* __restrict__ coors, const int* __restrict__ grid,
                            int* __restrict__ nbr) {
    int n = blockIdx.x * 256 + threadIdx.x;
    if (n >= N_VOX) return;
    int b = coors[n*4+0], z = coors[n*4+1]+1, y = coors[n*4+2]+1, x = coors[n*4+3]+1;
    int k = 0;
    for (int dz = -1; dz <= 1; ++dz)
        for (int dy = -1; dy <= 1; ++dy)
            for (int dx = -1; dx <= 1; ++dx) {
                nbr[k*N_VOX + n] = grid[((b*PD + z+dz)*PH + (y+dy))*PW + (x+dx)];
                ++k;
            }
}

// ---------------- combined weights: Wc[k][4c+j][o]; j=0 silu base, j=1..3 gauss(-1,0,1)
template<int CIN, int COUT>
__global__ void k_wcomb(const float* __restrict__ wb, const float* __restrict__ ws,
                        float* __restrict__ Wc) {
    const int CIN4 = CIN*4;
    int e = blockIdx.x * 256 + threadIdx.x;
    if (e >= KK*CIN4*COUT) return;
    int o  = e % COUT;
    int c4 = (e / COUT) % CIN4;
    int k  = e / (COUT * CIN4);
    int c = c4 >> 2, j = c4 & 3;
    float v;
    if (j == 0) v = wb[(k*CIN + c)*COUT + o];
    else        v = ws[((k*CIN + c)*3 + (j-1))*COUT + o];
    Wc[e] = v;
}

// ---------------- conv: pre[n][o] = sum_k sum_c4 phi(feat[nbr[k][n]])[c4] * Wc[k][c4][o]
template<int CIN, int COUT>
__global__ __launch_bounds__(256) void k_conv(
    const float* __restrict__ feat,   // [N_VOX, CIN]
    const int*   __restrict__ nbr,    // [KK, N_VOX]
    const float* __restrict__ Wc,     // [KK, 4*CIN, COUT]
    float*       __restrict__ pre)    // [N_VOX, COUT]
{
    constexpr int CIN4  = CIN * 4;
    constexpr int TO    = COUT / 4;     // threads along o
    constexpr int TV    = 256 / TO;     // threads along v
    constexpr int RV    = 64 / TV;      // voxels per thread
    constexpr int CHUNK = 64;           // c4 per LDS chunk (16 channels)
    constexpr int NCH   = CIN4 / CHUNK;
    constexpr int STRIDE = CHUNK + 4;   // LDS row stride (floats), 16B aligned, conflict-safe

    __shared__ float phi_s[64 * STRIDE];
    __shared__ int   idx_s[KK * 64];

    const int t    = threadIdx.x;
    const int base = blockIdx.x * 64;
    const int to = t % TO, tv = t / TO;
    const int o0 = to * 4;
    const int sv = t >> 2;   // staging voxel 0..63
    const int sq = t & 3;    // staging channel quad within 16-ch chunk

    float acc[RV][4];
    #pragma unroll
    for (int j = 0; j < RV; ++j)
        #pragma unroll
        for (int r = 0; r < 4; ++r) acc[j][r] = 0.f;

    // preload all 27 neighbor indices for this tile
    for (int i = t; i < KK*64; i += 256) {
        int vg = base + (i & 63);
        int k  = i >> 6;
        idx_s[i] = (vg < N_VOX) ? nbr[k*N_VOX + vg] : -1;
    }
    __syncthreads();

    for (int k = 0; k < KK; ++k) {
        for (int ch = 0; ch < NCH; ++ch) {
            // ---- stage phi chunk: channels [ch*16, ch*16+16) -> c4_local [0,64)
            {
                int idx = idx_s[k*64 + sv];
                float4 xv = make_float4(0.f, 0.f, 0.f, 0.f);
                if (idx >= 0)
                    xv = *(const float4*)&feat[idx*CIN + ch*16 + sq*4];
                float xs[4] = {xv.x, xv.y, xv.z, xv.w};
                #pragma unroll
                for (int dc = 0; dc < 4; ++dc) {
                    float x = xs[dc];
                    float sig = 1.f / (1.f + __expf(-x));
                    float4 p;
                    p.x = x * sig;                         // silu
                    p.y = __expf(-(x+1.f)*(x+1.f));        // center -1
                    p.z = __expf(-x*x);                    // center  0
                    p.w = __expf(-(x-1.f)*(x-1.f));        // center +1
                    *(float4*)&phi_s[sv*STRIDE + (sq*4+dc)*4] = p;
                }
            }
            __syncthreads();
            // ---- MAC over the 64 c4 values of this chunk
            const float* wk = Wc + (size_t)(k*CIN4 + ch*CHUNK) * COUT;
            #pragma unroll 2
            for (int c4 = 0; c4 < CHUNK; c4 += 4) {
                float4 w[4];
                #pragma unroll
                for (int cc = 0; cc < 4; ++cc)
                    w[cc] = *(const float4*)&wk[(c4+cc)*COUT + o0];
                #pragma unroll
                for (int j = 0; j < RV; ++j) {
                    float4 p = *(const float4*)&phi_s[(tv*RV + j)*STRIDE + c4];
                    acc[j][0] += p.x*w[0].x + p.y*w[1].x + p.z*w[2].x + p.w*w[3].x;
                    acc[j][1] += p.x*w[0].y + p.y*w[1].y + p.z*w[2].y + p.w*w[3].y;
                    acc[j][2] += p.x*w[0].z + p.y*w[1].z + p.z*w[2].z + p.w*w[3].z;
                    acc[j][3] += p.x*w[0].w + p.y*w[1].w + p.z*w[2].w + p.w*w[3].w;
                }
            }
            __syncthreads();
        }
    }

    #pragma unroll
    for (int j = 0; j < RV; ++j) {
        int vg = base + tv*RV + j;
        if (vg < N_VOX) {
            float4 r = make_float4(acc[j][0], acc[j][1], acc[j][2], acc[j][3]);
            *(float4*)&pre[(size_t)vg*COUT + o0] = r;
        }
    }
}

// ---------------- BN stats: sums[c] = sum, sums[COUT+c] = sumsq
template<int COUT>
__global__ void k_bnstats(const float* __restrict__ pre, float* __restrict__ sums) {
    __shared__ float s1[256], s2[256];
    int t = threadIdx.x;
    int stride = gridDim.x * 256;
    float a = 0.f, b = 0.f;
    for (int e = blockIdx.x*256 + t; e < N_VOX*COUT; e += stride) {
        float v = pre[e];
        a += v; b += v*v;
    }
    s1[t] = a; s2[t] = b;
    __syncthreads();
    if (t < COUT) {   // 256 % COUT == 0 and stride % COUT == 0 -> channel of thread t is t % COUT
        float x1 = 0.f, x2 = 0.f;
        for (int j = t; j < 256; j += COUT) { x1 += s1[j]; x2 += s2[j]; }
        atomicAdd(&sums[t], x1);
        atomicAdd(&sums[COUT + t], x2);
    }
}

template<int COUT>
__global__ void k_bnapply(float* __restrict__ pre, const float* __restrict__ sums,
                          const float* __restrict__ gm, const float* __restrict__ bt) {
    int e = blockIdx.x*256 + threadIdx.x;
    if (e >= N_VOX*COUT) return;
    int c = e % COUT;
    float mu  = sums[c] * (1.f / N_VOX);
    float var = sums[COUT + c] * (1.f / N_VOX) - mu*mu;
    float x = (pre[e] - mu) * rsqrtf(var + 1e-3f) * gm[c] + bt[c];
    pre[e] = fmaxf(x, 0.f);
}

// ---------------- dense fill: out[b][c*8+z][y][x]
__global__ void k_dense(const float* __restrict__ feat, const int* __restrict__ grid,
                        float* __restrict__ out) {
    int e = blockIdx.x*256 + threadIdx.x;
    if (e >= OUT_ELEMS) return;
    int x  = e % WW;
    int y  = (e / WW) % HH;
    int cz = (e / (WW*HH)) % (128*DD);
    int b  = e / (WW*HH*128*DD);
    int c = cz >> 3, z = cz & 7;
    int g = grid[((b*PD + z+1)*PH + (y+1))*PW + (x+1)];
    out[e] = (g >= 0) ? feat[(size_t)g*128 + c] : 0.f;
}

// ---------------- host side ----------------
template<int CIN, int COUT>
static void run_block(const float* feat_in, const float* wb, const float* ws,
                      const float* gm, const float* bt,
                      const int* nbr, float* Wc, float* sums, float* pre,
                      hipStream_t stream) {
    const int CIN4 = CIN*4;
    int wtot = KK*CIN4*COUT;
    k_wcomb<CIN,COUT><<<(wtot+255)/256, 256, 0, stream>>>(wb, ws, Wc);
    k_conv<CIN,COUT><<<(N_VOX+63)/64, 256, 0, stream>>>(feat_in, nbr, Wc, pre);
    hipMemsetAsync(sums, 0, 2*COUT*sizeof(float), stream);
    k_bnstats<COUT><<<64, 256, 0, stream>>>(pre, sums);
    k_bnapply<COUT><<<(N_VOX*COUT+255)/256, 256, 0, stream>>>(pre, sums, gm, bt);
}

extern "C" void kernel_launch(void* const* d_in, const int* in_sizes, int n_in,
                              void* d_out, int out_size, void* d_ws, size_t ws_size,
                              hipStream_t stream) {
    const float* vf    = (const float*)d_in[0];
    const int*   coors = (const int*)d_in[1];
    const float* wb[5] = {(const float*)d_in[3],  (const float*)d_in[7],
                          (const float*)d_in[11], (const float*)d_in[15],
                          (const float*)d_in[19]};
    const float* wsp[5]= {(const float*)d_in[4],  (const float*)d_in[8],
                          (const float*)d_in[12], (const float*)d_in[16],
                          (const float*)d_in[20]};
    const float* gm[5] = {(const float*)d_in[5],  (const float*)d_in[9],
                          (const float*)d_in[13], (const float*)d_in[17],
                          (const float*)d_in[21]};
    const float* bt[5] = {(const float*)d_in[6],  (const float*)d_in[10],
                          (const float*)d_in[14], (const float*)d_in[18],
                          (const float*)d_in[22]};

    // workspace layout (bump allocator, 256B aligned)
    char* p = (char*)d_ws;
    auto alloc = [&](size_t bytes) {
        char* r = p;
        p += (bytes + 255) & ~(size_t)255;
        return r;
    };
    int*   grid = (int*)  alloc((size_t)GRID_ELEMS * 4);
    int*   nbr  = (int*)  alloc((size_t)KK * N_VOX * 4);
    float* Wc   = (float*)alloc((size_t)KK * 256 * 128 * 4);   // max combined weights
    float* sums = (float*)alloc(2 * 128 * 4);
    float* fA   = (float*)alloc((size_t)N_VOX * 128 * 4);
    float* fB   = (float*)alloc((size_t)N_VOX * 128 * 4);

    // rulebook
    hipMemsetAsync(grid, 0xFF, (size_t)GRID_ELEMS * 4, stream);  // -1 everywhere
    k_scatter_grid<<<(N_VOX+255)/256, 256, 0, stream>>>(coors, grid);
    k_build_nbr  <<<(N_VOX+255)/256, 256, 0, stream>>>(coors, grid, nbr);

    // 5 KAN blocks (ping-pong fA/fB; BN applied in-place on conv output)
    run_block<16, 16 >(vf, wb[0], wsp[0], gm[0], bt[0], nbr, Wc, sums, fA, stream);
    run_block<16, 32 >(fA, wb[1], wsp[1], gm[1], bt[1], nbr, Wc, sums, fB, stream);
    run_block<32, 64 >(fB, wb[2], wsp[2], gm[2], bt[2], nbr, Wc, sums, fA, stream);
    run_block<64, 64 >(fA, wb[3], wsp[3], gm[3], bt[3], nbr, Wc, sums, fB, stream);
    run_block<64, 128>(fB, wb[4], wsp[4], gm[4], bt[4], nbr, Wc, sums, fA, stream);

    // dense output (writes every element exactly once; no separate zero pass)
    k_dense<<<(OUT_ELEMS+255)/256, 256, 0, stream>>>(fA, grid, (float*)d_out);
}

// Round 2
// 1305.941 us; speedup vs baseline: 3.0605x; 3.0605x over previous
//
#include <hip/hip_runtime.h>

#define N_VOX 50000
#define BATCH 2
#define DD 8
#define HH 160
#define WW 160
#define PD 10
#define PH 162
#define PW 162
#define KK 27
#define GRID_ELEMS (BATCH*PD*PH*PW)    // 524880
#define OUT_ELEMS (BATCH*128*DD*HH*WW) // 52,428,800

typedef __attribute__((ext_vector_type(8))) short short8v;
typedef __attribute__((ext_vector_type(4))) float float4v;

__device__ inline unsigned short f2bf(float f) {
    unsigned u = __float_as_uint(f);
    u += 0x7FFFu + ((u >> 16) & 1u);
    return (unsigned short)(u >> 16);
}

// ---------------- rulebook ----------------
__global__ void k_scatter_grid(const int* __restrict__ coors, int* __restrict__ grid) {
    int n = blockIdx.x * 256 + threadIdx.x;
    if (n >= N_VOX) return;
    int b = coors[n*4+0], z = coors[n*4+1], y = coors[n*4+2], x = coors[n*4+3];
    grid[((b*PD + z+1)*PH + (y+1))*PW + (x+1)] = n;
}

// nbr uses N_VOX as the "missing" sentinel -> pad row of phi (phi(0))
__global__ void k_build_nbr(const int* __restrict__ coors, const int* __restrict__ grid,
                            int* __restrict__ nbr) {
    int n = blockIdx.x * 256 + threadIdx.x;
    if (n >= N_VOX) return;
    int b = coors[n*4+0], z = coors[n*4+1]+1, y = coors[n*4+2]+1, x = coors[n*4+3]+1;
    int k = 0;
    for (int dz = -1; dz <= 1; ++dz)
        for (int dy = -1; dy <= 1; ++dy)
            for (int dx = -1; dx <= 1; ++dx) {
                int g = grid[((b*PD + z+dz)*PH + (y+dy))*PW + (x+dx)];
                nbr[k*N_VOX + n] = (g >= 0) ? g : N_VOX;
                ++k;
            }
}

// ---------------- phi: [N_VOX+1][4*CIN] bf16; pad row = phi(0) ----------------
template<int CIN>
__global__ void k_phi(const float* __restrict__ feat, unsigned short* __restrict__ phi) {
    int e = blockIdx.x * 256 + threadIdx.x;
    if (e >= (N_VOX + 1) * CIN) return;
    int n = e / CIN;
    float x = (n < N_VOX) ? feat[e] : 0.f;
    float sig = 1.f / (1.f + __expf(-x));
    ushort4 p;
    p.x = f2bf(x * sig);                          // silu base
    p.y = f2bf(__expf(-(x + 1.f) * (x + 1.f)));   // center -1
    p.z = f2bf(__expf(-x * x));                   // center  0
    p.w = f2bf(__expf(-(x - 1.f) * (x - 1.f)));   // center +1
    *(ushort4*)&phi[(size_t)e * 4] = p;           // phi[n][4c+j] == 4*e
}

// ---------------- weights pre-swizzled for MFMA B-operand: Wsw[kb][o][8] bf16
// global K index = k*4CIN + 4c + j ; kb = K/8, j8 = K%8
template<int CIN, int COUT>
__global__ void k_wswz(const float* __restrict__ wb, const float* __restrict__ ws,
                       unsigned short* __restrict__ Wsw) {
    constexpr int CIN4 = CIN * 4;
    int e = blockIdx.x * 256 + threadIdx.x;
    if (e >= KK * CIN4 * COUT) return;
    int j8   = e & 7;
    int rest = e >> 3;
    int o    = rest % COUT;
    int kb   = rest / COUT;
    int kabs = kb * 8 + j8;
    int k  = kabs / CIN4;
    int c4 = kabs % CIN4;
    int c = c4 >> 2, jj = c4 & 3;
    float v = (jj == 0) ? wb[(k * CIN + c) * COUT + o]
                        : ws[((k * CIN + c) * 3 + (jj - 1)) * COUT + o];
    Wsw[e] = f2bf(v);
}

// ---------------- MFMA conv: pre[n][o] = sum_K phi[nbr][K] * W[K][o]
// BM=128 (4 waves x 2 m-frags of 16), BN=COUT, BK=64, dbuf B in LDS,
// A gathered direct global->VGPR (16B/lane, 16x16x32 A-layout).
template<int CIN, int COUT>
__global__ __launch_bounds__(256) void k_conv_mfma(
    const unsigned short* __restrict__ phi,   // [(N_VOX+1), 4*CIN] bf16
    const int*            __restrict__ nbr,   // [KK, N_VOX], pad = N_VOX
    const unsigned short* __restrict__ Wsw,   // [Ktot/8, COUT, 8] bf16
    float*                __restrict__ pre)   // [N_VOX, COUT]
{
    constexpr int CIN4   = CIN * 4;
    constexpr int BK     = 64;
    constexpr int SPK    = CIN4 / BK;          // stages per k-offset (1,2,4)
    constexpr int NSTAGE = KK * SPK;
    constexpr int NF     = COUT / 16;
    constexpr int NCHUNK = (BK * COUT) / 8;    // 16B chunks per stage
    constexpr int NLD    = (NCHUNK + 255) / 256;

    __shared__ short Bs[2][BK * COUT];
    __shared__ int   idx_s[KK * 128];

    const int t    = threadIdx.x;
    const int base = blockIdx.x * 128;
    const int lane = t & 63, wv = t >> 6;
    const int l15  = lane & 15, q = lane >> 4;

    for (int i = t; i < KK * 128; i += 256) {
        int vg = base + (i & 127);
        idx_s[i] = (vg < N_VOX) ? nbr[(i >> 7) * N_VOX + vg] : N_VOX;
    }

    uint4 breg[NLD];
    auto stage_load = [&](int s) {
        const uint4* src = (const uint4*)(Wsw + (size_t)s * BK * COUT);
        #pragma unroll
        for (int i = 0; i < NLD; ++i) {
            int c = t + i * 256;
            if ((NCHUNK % 256 == 0) || c < NCHUNK) breg[i] = src[c];
        }
    };
    auto stage_write = [&](int buf) {
        uint4* dst = (uint4*)&Bs[buf][0];
        #pragma unroll
        for (int i = 0; i < NLD; ++i) {
            int c = t + i * 256;
            if ((NCHUNK % 256 == 0) || c < NCHUNK) dst[c] = breg[i];
        }
    };

    float4v acc[2][NF];
    #pragma unroll
    for (int mi = 0; mi < 2; ++mi)
        #pragma unroll
        for (int nf = 0; nf < NF; ++nf)
            acc[mi][nf] = (float4v){0.f, 0.f, 0.f, 0.f};

    stage_load(0);
    stage_write(0);
    __syncthreads();

    int rows[2] = {N_VOX, N_VOX};
    for (int s = 0; s < NSTAGE; ++s) {
        if (s + 1 < NSTAGE) stage_load(s + 1);     // async prefetch next B chunk
        if (s % SPK == 0) {
            int k = s / SPK;
            rows[0] = idx_s[k * 128 + wv * 32 + l15];
            rows[1] = idx_s[k * 128 + wv * 32 + 16 + l15];
        }
        const int c4s = (s % SPK) * BK;
        const short* bb = &Bs[s & 1][0];
        #pragma unroll
        for (int kk = 0; kk < BK / 32; ++kk) {
            const int aoff = c4s + kk * 32 + q * 8;
            short8v a0 = *(const short8v*)(phi + (size_t)rows[0] * CIN4 + aoff);
            short8v a1 = *(const short8v*)(phi + (size_t)rows[1] * CIN4 + aoff);
            #pragma unroll
            for (int nf = 0; nf < NF; ++nf) {
                short8v b = *(const short8v*)(bb + ((kk * 4 + q) * COUT + nf * 16 + l15) * 8);
                acc[0][nf] = __builtin_amdgcn_mfma_f32_16x16x32_bf16(a0, b, acc[0][nf], 0, 0, 0);
                acc[1][nf] = __builtin_amdgcn_mfma_f32_16x16x32_bf16(a1, b, acc[1][nf], 0, 0, 0);
            }
        }
        if (s + 1 < NSTAGE) stage_write((s + 1) & 1);  // other buffer: safe pre-barrier
        __syncthreads();
    }

    // C/D layout: col(o)=lane&15, row(m)=(lane>>4)*4+r  [measured m89]
    #pragma unroll
    for (int mi = 0; mi < 2; ++mi)
        #pragma unroll
        for (int nf = 0; nf < NF; ++nf)
            #pragma unroll
            for (int r = 0; r < 4; ++r) {
                int v = base + wv * 32 + mi * 16 + q * 4 + r;
                if (v < N_VOX) pre[(size_t)v * COUT + nf * 16 + l15] = acc[mi][nf][r];
            }
}

// ---------------- BN stats: sums[c] = sum, sums[COUT+c] = sumsq
template<int COUT>
__global__ void k_bnstats(const float* __restrict__ pre, float* __restrict__ sums) {
    __shared__ float s1[256], s2[256];
    int t = threadIdx.x;
    int stride = gridDim.x * 256;
    float a = 0.f, b = 0.f;
    for (int e = blockIdx.x*256 + t; e < N_VOX*COUT; e += stride) {
        float v = pre[e];
        a += v; b += v*v;
    }
    s1[t] = a; s2[t] = b;
    __syncthreads();
    if (t < COUT) {   // 256 % COUT == 0 -> channel of slot j is j % COUT
        float x1 = 0.f, x2 = 0.f;
        for (int j = t; j < 256; j += COUT) { x1 += s1[j]; x2 += s2[j]; }
        atomicAdd(&sums[t], x1);
        atomicAdd(&sums[COUT + t], x2);
    }
}

template<int COUT>
__global__ void k_bnapply(float* __restrict__ pre, const float* __restrict__ sums,
                          const float* __restrict__ gm, const float* __restrict__ bt) {
    int e = blockIdx.x*256 + threadIdx.x;
    if (e >= N_VOX*COUT) return;
    int c = e % COUT;
    float mu  = sums[c] * (1.f / N_VOX);
    float var = sums[COUT + c] * (1.f / N_VOX) - mu*mu;
    float x = (pre[e] - mu) * rsqrtf(var + 1e-3f) * gm[c] + bt[c];
    pre[e] = fmaxf(x, 0.f);
}

// ---------------- dense fill: out[b][c*8+z][y][x]
__global__ void k_dense(const float* __restrict__ feat, const int* __restrict__ grid,
                        float* __restrict__ out) {
    int e = blockIdx.x*256 + threadIdx.x;
    if (e >= OUT_ELEMS) return;
    int x  = e % WW;
    int y  = (e / WW) % HH;
    int cz = (e / (WW*HH)) % (128*DD);
    int b  = e / (WW*HH*128*DD);
    int c = cz >> 3, z = cz & 7;
    int g = grid[((b*PD + z+1)*PH + (y+1))*PW + (x+1)];
    out[e] = (g >= 0) ? feat[(size_t)g*128 + c] : 0.f;
}

// ---------------- host side ----------------
template<int CIN, int COUT>
static void run_block(const float* feat_in, const float* wb, const float* ws,
                      const float* gm, const float* bt, const int* nbr,
                      unsigned short* phi, unsigned short* Wsw, float* sums,
                      float* pre, hipStream_t stream) {
    constexpr int CIN4 = CIN * 4;
    int ptot = (N_VOX + 1) * CIN;
    k_phi<CIN><<<(ptot + 255) / 256, 256, 0, stream>>>(feat_in, phi);
    int wtot = KK * CIN4 * COUT;
    k_wswz<CIN, COUT><<<(wtot + 255) / 256, 256, 0, stream>>>(wb, ws, Wsw);
    k_conv_mfma<CIN, COUT><<<(N_VOX + 127) / 128, 256, 0, stream>>>(phi, nbr, Wsw, pre);
    hipMemsetAsync(sums, 0, 2 * COUT * sizeof(float), stream);
    k_bnstats<COUT><<<64, 256, 0, stream>>>(pre, sums);
    k_bnapply<COUT><<<(N_VOX * COUT + 255) / 256, 256, 0, stream>>>(pre, sums, gm, bt);
}

extern "C" void kernel_launch(void* const* d_in, const int* in_sizes, int n_in,
                              void* d_out, int out_size, void* d_ws, size_t ws_size,
                              hipStream_t stream) {
    const float* vf    = (const float*)d_in[0];
    const int*   coors = (const int*)d_in[1];
    const float* wb[5] = {(const float*)d_in[3],  (const float*)d_in[7],
                          (const float*)d_in[11], (const float*)d_in[15],
                          (const float*)d_in[19]};
    const float* wsp[5]= {(const float*)d_in[4],  (const float*)d_in[8],
                          (const float*)d_in[12], (const float*)d_in[16],
                          (const float*)d_in[20]};
    const float* gm[5] = {(const float*)d_in[5],  (const float*)d_in[9],
                          (const float*)d_in[13], (const float*)d_in[17],
                          (const float*)d_in[21]};
    const float* bt[5] = {(const float*)d_in[6],  (const float*)d_in[10],
                          (const float*)d_in[14], (const float*)d_in[18],
                          (const float*)d_in[22]};

    // workspace bump allocator (256B aligned) — total ~61 MB
    char* p = (char*)d_ws;
    auto alloc = [&](size_t bytes) {
        char* r = p;
        p += (bytes + 255) & ~(size_t)255;
        return r;
    };
    int*            grid = (int*)           alloc((size_t)GRID_ELEMS * 4);
    int*            nbr  = (int*)           alloc((size_t)KK * N_VOX * 4);
    unsigned short* Wsw  = (unsigned short*)alloc((size_t)KK * 256 * 128 * 2);
    unsigned short* phi  = (unsigned short*)alloc((size_t)(N_VOX + 1) * 256 * 2);
    float*          sums = (float*)         alloc(2 * 128 * 4);
    float*          fX   = (float*)         alloc((size_t)N_VOX * 128 * 4);

    // rulebook
    hipMemsetAsync(grid, 0xFF, (size_t)GRID_ELEMS * 4, stream);
    k_scatter_grid<<<(N_VOX+255)/256, 256, 0, stream>>>(coors, grid);
    k_build_nbr  <<<(N_VOX+255)/256, 256, 0, stream>>>(coors, grid, nbr);

    // 5 KAN blocks. Single fp32 feature buffer: phi is snapshotted from fX
    // before conv overwrites fX with the new pre-activation.
    run_block<16, 16 >(vf, wb[0], wsp[0], gm[0], bt[0], nbr, phi, Wsw, sums, fX, stream);
    run_block<16, 32 >(fX, wb[1], wsp[1], gm[1], bt[1], nbr, phi, Wsw, sums, fX, stream);
    run_block<32, 64 >(fX, wb[2], wsp[2], gm[2], bt[2], nbr, phi, Wsw, sums, fX, stream);
    run_block<64, 64 >(fX, wb[3], wsp[3], gm[3], bt[3], nbr, phi, Wsw, sums, fX, stream);
    run_block<64, 128>(fX, wb[4], wsp[4], gm[4], bt[4], nbr, phi, Wsw, sums, fX, stream);

    // dense output (writes every element exactly once)
    k_dense<<<(OUT_ELEMS+255)/256, 256, 0, stream>>>(fX, grid, (float*)d_out);
}

// Round 3
// 1210.123 us; speedup vs baseline: 3.3029x; 1.0792x over previous
//
#include <hip/hip_runtime.h>

#define N_VOX 50000
#define BATCH 2
#define DD 8
#define HH 160
#define WW 160
#define PD 10
#define PH 162
#define PW 162
#define KK 27
#define GRID_ELEMS (BATCH*PD*PH*PW)    // 524880
#define OUT_ELEMS (BATCH*128*DD*HH*WW) // 52,428,800

typedef __attribute__((ext_vector_type(8))) short short8v;
typedef __attribute__((ext_vector_type(4))) float float4v;

__device__ inline unsigned short f2bf(float f) {
    unsigned u = __float_as_uint(f);
    u += 0x7FFFu + ((u >> 16) & 1u);
    return (unsigned short)(u >> 16);
}

// ---------------- rulebook ----------------
__global__ void k_scatter_grid(const int* __restrict__ coors, int* __restrict__ grid) {
    int n = blockIdx.x * 256 + threadIdx.x;
    if (n >= N_VOX) return;
    int b = coors[n*4+0], z = coors[n*4+1], y = coors[n*4+2], x = coors[n*4+3];
    grid[((b*PD + z+1)*PH + (y+1))*PW + (x+1)] = n;
}

// nbr uses N_VOX as the "missing" sentinel -> pad row of phi (phi(0))
__global__ void k_build_nbr(const int* __restrict__ coors, const int* __restrict__ grid,
                            int* __restrict__ nbr) {
    int n = blockIdx.x * 256 + threadIdx.x;
    if (n >= N_VOX) return;
    int b = coors[n*4+0], z = coors[n*4+1]+1, y = coors[n*4+2]+1, x = coors[n*4+3]+1;
    int k = 0;
    for (int dz = -1; dz <= 1; ++dz)
        for (int dy = -1; dy <= 1; ++dy)
            for (int dx = -1; dx <= 1; ++dx) {
                int g = grid[((b*PD + z+dz)*PH + (y+dy))*PW + (x+dx)];
                nbr[k*N_VOX + n] = (g >= 0) ? g : N_VOX;
                ++k;
            }
}

// ---------------- phi: [N_VOX+1][4*CIN] bf16; pad row = phi(0) ----------------
template<int CIN>
__global__ void k_phi(const float* __restrict__ feat, unsigned short* __restrict__ phi) {
    int e = blockIdx.x * 256 + threadIdx.x;
    if (e >= (N_VOX + 1) * CIN) return;
    int n = e / CIN;
    float x = (n < N_VOX) ? feat[e] : 0.f;
    float sig = 1.f / (1.f + __expf(-x));
    ushort4 p;
    p.x = f2bf(x * sig);                          // silu base
    p.y = f2bf(__expf(-(x + 1.f) * (x + 1.f)));   // center -1
    p.z = f2bf(__expf(-x * x));                   // center  0
    p.w = f2bf(__expf(-(x - 1.f) * (x - 1.f)));   // center +1
    *(ushort4*)&phi[(size_t)e * 4] = p;           // phi[n][4c+j] == 4*e
}

// ---------------- weights pre-swizzled for MFMA B-operand: Wsw[kb][o][8] bf16
template<int CIN, int COUT>
__global__ void k_wswz(const float* __restrict__ wb, const float* __restrict__ ws,
                       unsigned short* __restrict__ Wsw) {
    constexpr int CIN4 = CIN * 4;
    int e = blockIdx.x * 256 + threadIdx.x;
    if (e >= KK * CIN4 * COUT) return;
    int j8   = e & 7;
    int rest = e >> 3;
    int o    = rest % COUT;
    int kb   = rest / COUT;
    int kabs = kb * 8 + j8;
    int k  = kabs / CIN4;
    int c4 = kabs % CIN4;
    int c = c4 >> 2, jj = c4 & 3;
    float v = (jj == 0) ? wb[(k * CIN + c) * COUT + o]
                        : ws[((k * CIN + c) * 3 + (jj - 1)) * COUT + o];
    Wsw[e] = f2bf(v);
}

// ---------------- MFMA conv with split-K: grid = NMB * SK blocks.
// Block (mb, sk) computes stages [sk*NSTAGE/SK, (sk+1)*NSTAGE/SK) for voxel
// tile mb, accumulating into pre via fp32 atomicAdd (pre pre-zeroed).
template<int CIN, int COUT, int SK>
__global__ __launch_bounds__(256, 4) void k_conv_mfma(
    const unsigned short* __restrict__ phi,   // [(N_VOX+1), 4*CIN] bf16
    const int*            __restrict__ nbr,   // [KK, N_VOX], pad = N_VOX
    const unsigned short* __restrict__ Wsw,   // [Ktot/8, COUT, 8] bf16
    float*                __restrict__ pre)   // [N_VOX, COUT] (zero-init)
{
    constexpr int CIN4   = CIN * 4;
    constexpr int BK     = 64;
    constexpr int SPK    = CIN4 / BK;          // stages per k-offset
    constexpr int NSTAGE = KK * SPK;
    constexpr int NF     = COUT / 16;
    constexpr int NCHUNK = (BK * COUT) / 8;    // 16B chunks per stage
    constexpr int NLD    = (NCHUNK + 255) / 256;
    constexpr int KLOC   = (NSTAGE + SK - 1) / SK;
    constexpr int NKLOC0 = (KLOC - 1) / SPK + 2;
    constexpr int NKLOC  = NKLOC0 < KK ? NKLOC0 : KK;

    __shared__ short Bs[2][BK * COUT];
    __shared__ int   idx_s[NKLOC * 128];

    const int t    = threadIdx.x;
    const int mb   = blockIdx.x / SK;
    const int sk   = blockIdx.x % SK;
    const int base = mb * 128;
    const int s0   = (sk * NSTAGE) / SK;
    const int s1   = ((sk + 1) * NSTAGE) / SK;
    const int k0   = s0 / SPK;
    const int k1   = (s1 - 1) / SPK;           // inclusive
    const int lane = t & 63, wv = t >> 6;
    const int l15  = lane & 15, q = lane >> 4;

    uint4 breg[NLD];
    auto stage_load = [&](int s) {
        const uint4* src = (const uint4*)(Wsw + (size_t)s * BK * COUT);
        #pragma unroll
        for (int i = 0; i < NLD; ++i) {
            int c = t + i * 256;
            if ((NCHUNK % 256 == 0) || c < NCHUNK) breg[i] = src[c];
        }
    };
    auto stage_write = [&](int buf) {
        uint4* dst = (uint4*)&Bs[buf][0];
        #pragma unroll
        for (int i = 0; i < NLD; ++i) {
            int c = t + i * 256;
            if ((NCHUNK % 256 == 0) || c < NCHUNK) dst[c] = breg[i];
        }
    };

    stage_load(s0);
    for (int i = t; i < (k1 - k0 + 1) * 128; i += 256) {
        int vg = base + (i & 127);
        idx_s[i] = (vg < N_VOX) ? nbr[(k0 + (i >> 7)) * N_VOX + vg] : N_VOX;
    }
    stage_write(0);
    __syncthreads();

    float4v acc[2][NF];
    #pragma unroll
    for (int mi = 0; mi < 2; ++mi)
        #pragma unroll
        for (int nf = 0; nf < NF; ++nf)
            acc[mi][nf] = (float4v){0.f, 0.f, 0.f, 0.f};

    int rows[2] = {N_VOX, N_VOX};
    for (int s = s0; s < s1; ++s) {
        if (s + 1 < s1) stage_load(s + 1);     // prefetch next B chunk
        if (s == s0 || s % SPK == 0) {
            int kl = s / SPK - k0;
            rows[0] = idx_s[kl * 128 + wv * 32 + l15];
            rows[1] = idx_s[kl * 128 + wv * 32 + 16 + l15];
        }
        const int c4s = (s % SPK) * BK;
        // issue all 4 A-gathers together before the MFMA loop
        short8v A[2][2];
        #pragma unroll
        for (int kk = 0; kk < 2; ++kk) {
            const int aoff = c4s + kk * 32 + q * 8;
            A[kk][0] = *(const short8v*)(phi + (size_t)rows[0] * CIN4 + aoff);
            A[kk][1] = *(const short8v*)(phi + (size_t)rows[1] * CIN4 + aoff);
        }
        const short* bb = &Bs[(s - s0) & 1][0];
        #pragma unroll
        for (int kk = 0; kk < 2; ++kk) {
            #pragma unroll
            for (int nf = 0; nf < NF; ++nf) {
                short8v b = *(const short8v*)(bb + ((kk * 4 + q) * COUT + nf * 16 + l15) * 8);
                acc[0][nf] = __builtin_amdgcn_mfma_f32_16x16x32_bf16(A[kk][0], b, acc[0][nf], 0, 0, 0);
                acc[1][nf] = __builtin_amdgcn_mfma_f32_16x16x32_bf16(A[kk][1], b, acc[1][nf], 0, 0, 0);
            }
        }
        if (s + 1 < s1) stage_write((s + 1 - s0) & 1);  // other buffer: pre-barrier safe
        __syncthreads();
    }

    // C/D layout: col(o)=lane&15, row(m)=(lane>>4)*4+r  [measured m89]
    #pragma unroll
    for (int mi = 0; mi < 2; ++mi)
        #pragma unroll
        for (int nf = 0; nf < NF; ++nf)
            #pragma unroll
            for (int r = 0; r < 4; ++r) {
                int v = base + wv * 32 + mi * 16 + q * 4 + r;
                if (v < N_VOX)
                    atomicAdd(&pre[(size_t)v * COUT + nf * 16 + l15], acc[mi][nf][r]);
            }
}

// ---------------- BN stats: sums[c] = sum, sums[COUT+c] = sumsq
template<int COUT>
__global__ void k_bnstats(const float* __restrict__ pre, float* __restrict__ sums) {
    __shared__ float s1[256], s2[256];
    int t = threadIdx.x;
    int stride = gridDim.x * 256;
    float a = 0.f, b = 0.f;
    for (int e = blockIdx.x*256 + t; e < N_VOX*COUT; e += stride) {
        float v = pre[e];
        a += v; b += v*v;
    }
    s1[t] = a; s2[t] = b;
    __syncthreads();
    if (t < COUT) {   // 256 % COUT == 0 -> channel of slot j is j % COUT
        float x1 = 0.f, x2 = 0.f;
        for (int j = t; j < 256; j += COUT) { x1 += s1[j]; x2 += s2[j]; }
        atomicAdd(&sums[t], x1);
        atomicAdd(&sums[COUT + t], x2);
    }
}

template<int COUT>
__global__ void k_bnapply(float* __restrict__ pre, const float* __restrict__ sums,
                          const float* __restrict__ gm, const float* __restrict__ bt) {
    int e = blockIdx.x*256 + threadIdx.x;
    if (e >= N_VOX*COUT) return;
    int c = e % COUT;
    float mu  = sums[c] * (1.f / N_VOX);
    float var = sums[COUT + c] * (1.f / N_VOX) - mu*mu;
    float x = (pre[e] - mu) * rsqrtf(var + 1e-3f) * gm[c] + bt[c];
    pre[e] = fmaxf(x, 0.f);
}

// ---------------- dense fill: out[b][c*8+z][y][x]
__global__ void k_dense(const float* __restrict__ feat, const int* __restrict__ grid,
                        float* __restrict__ out) {
    int e = blockIdx.x*256 + threadIdx.x;
    if (e >= OUT_ELEMS) return;
    int x  = e % WW;
    int y  = (e / WW) % HH;
    int cz = (e / (WW*HH)) % (128*DD);
    int b  = e / (WW*HH*128*DD);
    int c = cz >> 3, z = cz & 7;
    int g = grid[((b*PD + z+1)*PH + (y+1))*PW + (x+1)];
    out[e] = (g >= 0) ? feat[(size_t)g*128 + c] : 0.f;
}

// ---------------- host side ----------------
template<int CIN, int COUT, int SK>
static void run_block(const float* feat_in, const float* wb, const float* ws,
                      const float* gm, const float* bt, const int* nbr,
                      unsigned short* phi, unsigned short* Wsw, float* sums,
                      float* pre, hipStream_t stream) {
    constexpr int CIN4 = CIN * 4;
    int ptot = (N_VOX + 1) * CIN;
    k_phi<CIN><<<(ptot + 255) / 256, 256, 0, stream>>>(feat_in, phi);
    int wtot = KK * CIN4 * COUT;
    k_wswz<CIN, COUT><<<(wtot + 255) / 256, 256, 0, stream>>>(wb, ws, Wsw);
    hipMemsetAsync(pre, 0, (size_t)N_VOX * COUT * sizeof(float), stream);
    int nmb = (N_VOX + 127) / 128;
    k_conv_mfma<CIN, COUT, SK><<<nmb * SK, 256, 0, stream>>>(phi, nbr, Wsw, pre);
    hipMemsetAsync(sums, 0, 2 * COUT * sizeof(float), stream);
    k_bnstats<COUT><<<64, 256, 0, stream>>>(pre, sums);
    k_bnapply<COUT><<<(N_VOX * COUT + 255) / 256, 256, 0, stream>>>(pre, sums, gm, bt);
}

extern "C" void kernel_launch(void* const* d_in, const int* in_sizes, int n_in,
                              void* d_out, int out_size, void* d_ws, size_t ws_size,
                              hipStream_t stream) {
    const float* vf    = (const float*)d_in[0];
    const int*   coors = (const int*)d_in[1];
    const float* wb[5] = {(const float*)d_in[3],  (const float*)d_in[7],
                          (const float*)d_in[11], (const float*)d_in[15],
                          (const float*)d_in[19]};
    const float* wsp[5]= {(const float*)d_in[4],  (const float*)d_in[8],
                          (const float*)d_in[12], (const float*)d_in[16],
                          (const float*)d_in[20]};
    const float* gm[5] = {(const float*)d_in[5],  (const float*)d_in[9],
                          (const float*)d_in[13], (const float*)d_in[17],
                          (const float*)d_in[21]};
    const float* bt[5] = {(const float*)d_in[6],  (const float*)d_in[10],
                          (const float*)d_in[14], (const float*)d_in[18],
                          (const float*)d_in[22]};

    // workspace bump allocator (256B aligned) — total ~61 MB
    char* p = (char*)d_ws;
    auto alloc = [&](size_t bytes) {
        char* r = p;
        p += (bytes + 255) & ~(size_t)255;
        return r;
    };
    int*            grid = (int*)           alloc((size_t)GRID_ELEMS * 4);
    int*            nbr  = (int*)           alloc((size_t)KK * N_VOX * 4);
    unsigned short* Wsw  = (unsigned short*)alloc((size_t)KK * 256 * 128 * 2);
    unsigned short* phi  = (unsigned short*)alloc((size_t)(N_VOX + 1) * 256 * 2);
    float*          sums = (float*)         alloc(2 * 128 * 4);
    float*          fX   = (float*)         alloc((size_t)N_VOX * 128 * 4);

    // rulebook
    hipMemsetAsync(grid, 0xFF, (size_t)GRID_ELEMS * 4, stream);
    k_scatter_grid<<<(N_VOX+255)/256, 256, 0, stream>>>(coors, grid);
    k_build_nbr  <<<(N_VOX+255)/256, 256, 0, stream>>>(coors, grid, nbr);

    // 5 KAN blocks; phi snapshots fX before conv overwrites it.
    run_block<16, 16,  2>(vf, wb[0], wsp[0], gm[0], bt[0], nbr, phi, Wsw, sums, fX, stream);
    run_block<16, 32,  2>(fX, wb[1], wsp[1], gm[1], bt[1], nbr, phi, Wsw, sums, fX, stream);
    run_block<32, 64,  3>(fX, wb[2], wsp[2], gm[2], bt[2], nbr, phi, Wsw, sums, fX, stream);
    run_block<64, 64,  4>(fX, wb[3], wsp[3], gm[3], bt[3], nbr, phi, Wsw, sums, fX, stream);
    run_block<64, 128, 4>(fX, wb[4], wsp[4], gm[4], bt[4], nbr, phi, Wsw, sums, fX, stream);

    // dense output (writes every element exactly once)
    k_dense<<<(OUT_ELEMS+255)/256, 256, 0, stream>>>(fX, grid, (float*)d_out);
}

// Round 4
// 1070.154 us; speedup vs baseline: 3.7349x; 1.1308x over previous
//
#include <hip/hip_runtime.h>

#define N_VOX 50000
#define BATCH 2
#define DD 8
#define HH 160
#define WW 160
#define PD 10
#define PH 162
#define PW 162
#define KK 27
#define NCELL (BATCH*DD*HH*WW)         // 409600 = 400*1024
#define GRID_ELEMS (BATCH*PD*PH*PW)    // 524880
#define OUT_ELEMS (BATCH*128*DD*HH*WW) // 52,428,800

typedef __attribute__((ext_vector_type(8))) short short8v;
typedef __attribute__((ext_vector_type(4))) float float4v;

__device__ inline unsigned short f2bf(float f) {
    unsigned u = __float_as_uint(f);
    u += 0x7FFFu + ((u >> 16) & 1u);
    return (unsigned short)(u >> 16);
}

// ============ spatial sort: occupancy flags -> prefix sum -> permutation ====
__global__ void k_flags(const int* __restrict__ coors, int* __restrict__ flags) {
    int n = blockIdx.x * 256 + threadIdx.x;
    if (n >= N_VOX) return;
    int b = coors[n*4+0], z = coors[n*4+1], y = coors[n*4+2], x = coors[n*4+3];
    flags[((b*DD + z)*HH + y)*WW + x] = 1;
}

__global__ void k_scan1(const int* __restrict__ flags, int* __restrict__ scanout,
                        int* __restrict__ bsums) {
    __shared__ int s[256];
    int t = threadIdx.x, blk = blockIdx.x;
    int4 v = ((const int4*)(flags + blk*1024))[t];
    int tsum = v.x + v.y + v.z + v.w;
    s[t] = tsum; __syncthreads();
    for (int off = 1; off < 256; off <<= 1) {
        int x = (t >= off) ? s[t-off] : 0;
        __syncthreads(); s[t] += x; __syncthreads();
    }
    int excl = s[t] - tsum;
    int4 o; o.x = excl; o.y = excl + v.x; o.z = o.y + v.y; o.w = o.z + v.z;
    ((int4*)(scanout + blk*1024))[t] = o;
    if (t == 255) bsums[blk] = s[255];
}

__global__ void k_scan2(int* __restrict__ bsums) {
    __shared__ int s[512];
    int t = threadIdx.x;
    int orig = (t < 400) ? bsums[t] : 0;
    s[t] = orig; __syncthreads();
    for (int off = 1; off < 512; off <<= 1) {
        int x = (t >= off) ? s[t-off] : 0;
        __syncthreads(); s[t] += x; __syncthreads();
    }
    if (t < 400) bsums[t] = s[t] - orig;
}

__global__ void k_pos(const int* __restrict__ coors, const int* __restrict__ scanout,
                      const int* __restrict__ bsums, int* __restrict__ pos_of,
                      int* __restrict__ vox_at) {
    int n = blockIdx.x * 256 + threadIdx.x;
    if (n >= N_VOX) return;
    int b = coors[n*4+0], z = coors[n*4+1], y = coors[n*4+2], x = coors[n*4+3];
    int lin = ((b*DD + z)*HH + y)*WW + x;
    int pos = scanout[lin] + bsums[lin >> 10];
    pos_of[n] = pos;
    vox_at[pos] = n;
}

__global__ void k_gridP(const int* __restrict__ coors, const int* __restrict__ pos_of,
                        int* __restrict__ gridP) {
    int n = blockIdx.x * 256 + threadIdx.x;
    if (n >= N_VOX) return;
    int b = coors[n*4+0], z = coors[n*4+1], y = coors[n*4+2], x = coors[n*4+3];
    gridP[((b*PD + z+1)*PH + (y+1))*PW + (x+1)] = pos_of[n];
}

__global__ void k_nbrP(const int* __restrict__ coors, const int* __restrict__ pos_of,
                       const int* __restrict__ gridP, int* __restrict__ nbrP) {
    int n = blockIdx.x * 256 + threadIdx.x;
    if (n >= N_VOX) return;
    int b = coors[n*4+0], z = coors[n*4+1]+1, y = coors[n*4+2]+1, x = coors[n*4+3]+1;
    int i = pos_of[n];
    int k = 0;
    for (int dz = -1; dz <= 1; ++dz)
        for (int dy = -1; dy <= 1; ++dy)
            for (int dx = -1; dx <= 1; ++dx) {
                int g = gridP[((b*PD + z+dz)*PH + (y+dy))*PW + (x+dx)];
                nbrP[k*N_VOX + i] = (g >= 0) ? g : N_VOX;
                ++k;
            }
}

// ============ phi: [N_VOX+1][4*CIN] bf16 (permuted rows); pad row = phi(0) ==
__global__ void k_phi0(const float* __restrict__ vf, const int* __restrict__ vox_at,
                       unsigned short* __restrict__ phi) {
    int e = blockIdx.x * 256 + threadIdx.x;
    if (e >= (N_VOX + 1) * 16) return;
    int i = e / 16, c = e % 16;
    float x = 0.f;
    if (i < N_VOX) x = vf[(size_t)vox_at[i] * 16 + c];
    float sig = 1.f / (1.f + __expf(-x));
    ushort4 p;
    p.x = f2bf(x * sig);
    p.y = f2bf(__expf(-(x + 1.f) * (x + 1.f)));
    p.z = f2bf(__expf(-x * x));
    p.w = f2bf(__expf(-(x - 1.f) * (x - 1.f)));
    *(ushort4*)&phi[(size_t)e * 4] = p;
}

// ============ weights pre-swizzled for MFMA B: Wsw[kb][o][8] bf16 ============
template<int CIN, int COUT>
__global__ void k_wswz(const float* __restrict__ wb, const float* __restrict__ ws,
                       unsigned short* __restrict__ Wsw) {
    constexpr int CIN4 = CIN * 4;
    int e = blockIdx.x * 256 + threadIdx.x;
    if (e >= KK * CIN4 * COUT) return;
    int j8   = e & 7;
    int rest = e >> 3;
    int o    = rest % COUT;
    int kb   = rest / COUT;
    int kabs = kb * 8 + j8;
    int k  = kabs / CIN4;
    int c4 = kabs % CIN4;
    int c = c4 >> 2, jj = c4 & 3;
    float v = (jj == 0) ? wb[(k * CIN + c) * COUT + o]
                        : ws[((k * CIN + c) * 3 + (jj - 1)) * COUT + o];
    Wsw[e] = f2bf(v);
}

// ============ barrier-free MFMA conv, split over COUT frag-halves ===========
// Block (mb,h): 128 voxel rows, COUT-columns half h. No LDS, no barriers;
// 1-deep register pipeline on A; rows prefetched one k-offset ahead.
template<int CIN, int COUT, int NSPL>
__global__ __launch_bounds__(256, (COUT >= 128 ? 3 : 4)) void k_conv_mfma(
    const unsigned short* __restrict__ phi,   // [(N_VOX+1), 4*CIN] bf16
    const int*            __restrict__ nbrP,  // [KK, N_VOX] permuted, pad = N_VOX
    const unsigned short* __restrict__ Wsw,   // [Ktot/8, COUT, 8] bf16
    float*                __restrict__ pre)   // [N_VOX, COUT]
{
    constexpr int CIN4   = CIN * 4;
    constexpr int BK     = 64;
    constexpr int SPK    = CIN4 / BK;          // 1,1,2,4,4
    constexpr int NSTAGE = KK * SPK;
    constexpr int NF     = COUT / 16;
    constexpr int NFW    = NF / NSPL;
    constexpr int NMB    = (N_VOX + 127) / 128;
    constexpr int NBLK   = NMB * NSPL;
    constexpr int PERX   = (NBLK + 7) / 8;

    // XCD swizzle: contiguous (mb,h) runs per XCD for L2 gather reuse
    int lb = blockIdx.x;
    int linear = (lb & 7) * PERX + (lb >> 3);
    if (linear >= NBLK) return;
    const int mb = linear / NSPL, h = linear % NSPL;

    const int t = threadIdx.x, lane = t & 63, wv = t >> 6;
    const int l15 = lane & 15, q = lane >> 4;
    const int base = mb * 128;
    const int vg0 = base + wv * 32 + l15, vg1 = vg0 + 16;
    const int ob = h * NFW * 16;

    float4v acc[2][NFW];
    #pragma unroll
    for (int mi = 0; mi < 2; ++mi)
        #pragma unroll
        for (int nf = 0; nf < NFW; ++nf)
            acc[mi][nf] = (float4v){0.f, 0.f, 0.f, 0.f};

    int rows[2], rowsN[2];
    short8v A[2][2], An[2][2];

    rows[0] = (vg0 < N_VOX) ? nbrP[vg0] : N_VOX;                 // k=0
    rows[1] = (vg1 < N_VOX) ? nbrP[vg1] : N_VOX;
    rowsN[0] = (vg0 < N_VOX) ? nbrP[N_VOX + vg0] : N_VOX;        // k=1
    rowsN[1] = (vg1 < N_VOX) ? nbrP[N_VOX + vg1] : N_VOX;
    {
        const unsigned short* p0 = phi + (size_t)rows[0] * CIN4 + q * 8;
        const unsigned short* p1 = phi + (size_t)rows[1] * CIN4 + q * 8;
        A[0][0] = *(const short8v*)p0;        A[0][1] = *(const short8v*)p1;
        A[1][0] = *(const short8v*)(p0 + 32); A[1][1] = *(const short8v*)(p1 + 32);
    }

    for (int s = 0; s < NSTAGE; ++s) {
        if (s + 1 < NSTAGE) {
            const int sp = s + 1;
            const int c4n = (sp % SPK) * BK;
            if (sp % SPK == 0) { rows[0] = rowsN[0]; rows[1] = rowsN[1]; }
            const unsigned short* p0 = phi + (size_t)rows[0] * CIN4 + c4n + q * 8;
            const unsigned short* p1 = phi + (size_t)rows[1] * CIN4 + c4n + q * 8;
            An[0][0] = *(const short8v*)p0;        An[0][1] = *(const short8v*)p1;
            An[1][0] = *(const short8v*)(p0 + 32); An[1][1] = *(const short8v*)(p1 + 32);
            if (sp % SPK == 0) {
                int k2 = sp / SPK + 1;
                if (k2 < KK) {
                    rowsN[0] = (vg0 < N_VOX) ? nbrP[k2 * N_VOX + vg0] : N_VOX;
                    rowsN[1] = (vg1 < N_VOX) ? nbrP[k2 * N_VOX + vg1] : N_VOX;
                }
            }
        }
        const unsigned short* bs = Wsw + (size_t)s * BK * COUT
                                       + (size_t)(q * COUT + ob + l15) * 8;
        #pragma unroll
        for (int kk = 0; kk < 2; ++kk) {
            #pragma unroll
            for (int nf = 0; nf < NFW; ++nf) {
                short8v bfr = *(const short8v*)(bs + (size_t)(kk * 4 * COUT + nf * 16) * 8);
                acc[0][nf] = __builtin_amdgcn_mfma_f32_16x16x32_bf16(A[kk][0], bfr, acc[0][nf], 0, 0, 0);
                acc[1][nf] = __builtin_amdgcn_mfma_f32_16x16x32_bf16(A[kk][1], bfr, acc[1][nf], 0, 0, 0);
            }
        }
        #pragma unroll
        for (int kk = 0; kk < 2; ++kk) { A[kk][0] = An[kk][0]; A[kk][1] = An[kk][1]; }
    }

    // C/D layout: col(o)=lane&15, row(m)=(lane>>4)*4+r  [measured m89]
    #pragma unroll
    for (int mi = 0; mi < 2; ++mi)
        #pragma unroll
        for (int nf = 0; nf < NFW; ++nf)
            #pragma unroll
            for (int r = 0; r < 4; ++r) {
                int v = base + wv * 32 + mi * 16 + q * 4 + r;
                if (v < N_VOX)
                    pre[(size_t)v * COUT + ob + nf * 16 + l15] = acc[mi][nf][r];
            }
}

// ============ BN stats ============
template<int COUT>
__global__ void k_bnstats(const float* __restrict__ pre, float* __restrict__ sums) {
    __shared__ float s1[256], s2[256];
    int t = threadIdx.x;
    int stride = gridDim.x * 256;
    float a = 0.f, b = 0.f;
    for (int e = blockIdx.x*256 + t; e < N_VOX*COUT; e += stride) {
        float v = pre[e];
        a += v; b += v*v;
    }
    s1[t] = a; s2[t] = b;
    __syncthreads();
    if (t < COUT) {
        float x1 = 0.f, x2 = 0.f;
        for (int j = t; j < 256; j += COUT) { x1 += s1[j]; x2 += s2[j]; }
        atomicAdd(&sums[t], x1);
        atomicAdd(&sums[COUT + t], x2);
    }
}

// BN+ReLU fused with next layer's phi (incl. pad row = phi(0))
template<int COUT>
__global__ void k_bnapply_phi(const float* __restrict__ pre, const float* __restrict__ sums,
                              const float* __restrict__ gm, const float* __restrict__ bt,
                              unsigned short* __restrict__ phi) {
    int e = blockIdx.x*256 + threadIdx.x;
    if (e >= (N_VOX + 1) * COUT) return;
    int i = e / COUT, c = e % COUT;
    float x = 0.f;
    if (i < N_VOX) {
        float mu  = sums[c] * (1.f / N_VOX);
        float var = sums[COUT + c] * (1.f / N_VOX) - mu*mu;
        float v = (pre[(size_t)i*COUT + c] - mu) * rsqrtf(var + 1e-3f) * gm[c] + bt[c];
        x = fmaxf(v, 0.f);
    }
    float sig = 1.f / (1.f + __expf(-x));
    ushort4 p;
    p.x = f2bf(x * sig);
    p.y = f2bf(__expf(-(x + 1.f) * (x + 1.f)));
    p.z = f2bf(__expf(-x * x));
    p.w = f2bf(__expf(-(x - 1.f) * (x - 1.f)));
    *(ushort4*)&phi[(size_t)e * 4] = p;
}

template<int COUT>
__global__ void k_bnapply_f32(float* __restrict__ pre, const float* __restrict__ sums,
                              const float* __restrict__ gm, const float* __restrict__ bt) {
    int e = blockIdx.x*256 + threadIdx.x;
    if (e >= N_VOX*COUT) return;
    int c = e % COUT;
    float mu  = sums[c] * (1.f / N_VOX);
    float var = sums[COUT + c] * (1.f / N_VOX) - mu*mu;
    float x = (pre[e] - mu) * rsqrtf(var + 1e-3f) * gm[c] + bt[c];
    pre[e] = fmaxf(x, 0.f);
}

// ============ dense fill: out[b][c*8+z][y][x] (gridP holds permuted pos) ====
__global__ void k_dense(const float* __restrict__ feat, const int* __restrict__ gridP,
                        float* __restrict__ out) {
    int e = blockIdx.x*256 + threadIdx.x;
    if (e >= OUT_ELEMS) return;
    int x  = e % WW;
    int y  = (e / WW) % HH;
    int cz = (e / (WW*HH)) % (128*DD);
    int b  = e / (WW*HH*128*DD);
    int c = cz >> 3, z = cz & 7;
    int g = gridP[((b*PD + z+1)*PH + (y+1))*PW + (x+1)];
    out[e] = (g >= 0) ? feat[(size_t)g*128 + c] : 0.f;
}

// ============ host side ============
template<int CIN, int COUT, int NSPL>
static void launch_conv(const unsigned short* phi, const int* nbrP,
                        const unsigned short* Wsw, float* pre, hipStream_t stream) {
    constexpr int NMB  = (N_VOX + 127) / 128;
    constexpr int NBLK = NMB * NSPL;
    constexpr int GRID = ((NBLK + 7) / 8) * 8;
    k_conv_mfma<CIN, COUT, NSPL><<<GRID, 256, 0, stream>>>(phi, nbrP, Wsw, pre);
}

template<int CIN, int COUT, int NSPL>
static void run_block(const float* wb, const float* ws, const float* gm, const float* bt,
                      const int* nbrP, unsigned short* phi, unsigned short* Wsw,
                      float* sums, float* pre, bool last, hipStream_t stream) {
    int wtot = KK * CIN * 4 * COUT;
    k_wswz<CIN, COUT><<<(wtot + 255) / 256, 256, 0, stream>>>(wb, ws, Wsw);
    launch_conv<CIN, COUT, NSPL>(phi, nbrP, Wsw, pre, stream);
    hipMemsetAsync(sums, 0, 2 * COUT * sizeof(float), stream);
    k_bnstats<COUT><<<64, 256, 0, stream>>>(pre, sums);
    if (last) {
        k_bnapply_f32<COUT><<<(N_VOX * COUT + 255) / 256, 256, 0, stream>>>(pre, sums, gm, bt);
    } else {
        int n = (N_VOX + 1) * COUT;
        k_bnapply_phi<COUT><<<(n + 255) / 256, 256, 0, stream>>>(pre, sums, gm, bt, phi);
    }
}

extern "C" void kernel_launch(void* const* d_in, const int* in_sizes, int n_in,
                              void* d_out, int out_size, void* d_ws, size_t ws_size,
                              hipStream_t stream) {
    const float* vf    = (const float*)d_in[0];
    const int*   coors = (const int*)d_in[1];
    const float* wb[5] = {(const float*)d_in[3],  (const float*)d_in[7],
                          (const float*)d_in[11], (const float*)d_in[15],
                          (const float*)d_in[19]};
    const float* wsp[5]= {(const float*)d_in[4],  (const float*)d_in[8],
                          (const float*)d_in[12], (const float*)d_in[16],
                          (const float*)d_in[20]};
    const float* gm[5] = {(const float*)d_in[5],  (const float*)d_in[9],
                          (const float*)d_in[13], (const float*)d_in[17],
                          (const float*)d_in[21]};
    const float* bt[5] = {(const float*)d_in[6],  (const float*)d_in[10],
                          (const float*)d_in[14], (const float*)d_in[18],
                          (const float*)d_in[22]};

    // workspace bump allocator (256B aligned), ~66 MB total
    char* p = (char*)d_ws;
    auto alloc = [&](size_t bytes) {
        char* r = p;
        p += (bytes + 255) & ~(size_t)255;
        return r;
    };
    int*            flags   = (int*)           alloc((size_t)NCELL * 4);
    int*            scanout = (int*)           alloc((size_t)NCELL * 4);
    int*            bsums   = (int*)           alloc(512 * 4);
    int*            pos_of  = (int*)           alloc((size_t)N_VOX * 4);
    int*            vox_at  = (int*)           alloc((size_t)N_VOX * 4);
    int*            gridP   = (int*)           alloc((size_t)GRID_ELEMS * 4);
    int*            nbrP    = (int*)           alloc((size_t)KK * N_VOX * 4);
    unsigned short* Wsw0    = (unsigned short*)alloc((size_t)KK * 64  * 16  * 2);
    unsigned short* Wsw1    = (unsigned short*)alloc((size_t)KK * 64  * 32  * 2);
    unsigned short* Wsw2    = (unsigned short*)alloc((size_t)KK * 128 * 64  * 2);
    unsigned short* Wsw3    = (unsigned short*)alloc((size_t)KK * 256 * 64  * 2);
    unsigned short* Wsw4    = (unsigned short*)alloc((size_t)KK * 256 * 128 * 2);
    unsigned short* phi     = (unsigned short*)alloc((size_t)(N_VOX + 1) * 256 * 2);
    float*          sums    = (float*)         alloc(2 * 128 * 4);
    float*          pre     = (float*)         alloc((size_t)N_VOX * 128 * 4);

    // ---- spatial permutation + rulebook
    hipMemsetAsync(flags, 0, (size_t)NCELL * 4, stream);
    hipMemsetAsync(gridP, 0xFF, (size_t)GRID_ELEMS * 4, stream);
    k_flags<<<(N_VOX+255)/256, 256, 0, stream>>>(coors, flags);
    k_scan1<<<NCELL/1024, 256, 0, stream>>>(flags, scanout, bsums);
    k_scan2<<<1, 512, 0, stream>>>(bsums);
    k_pos  <<<(N_VOX+255)/256, 256, 0, stream>>>(coors, scanout, bsums, pos_of, vox_at);
    k_gridP<<<(N_VOX+255)/256, 256, 0, stream>>>(coors, pos_of, gridP);
    k_nbrP <<<(N_VOX+255)/256, 256, 0, stream>>>(coors, pos_of, gridP, nbrP);
    {
        int n = (N_VOX + 1) * 16;
        k_phi0<<<(n + 255) / 256, 256, 0, stream>>>(vf, vox_at, phi);
    }

    // ---- 5 KAN blocks (all state permuted; phi overwritten in stream order)
    run_block<16, 16,  1>(wb[0], wsp[0], gm[0], bt[0], nbrP, phi, Wsw0, sums, pre, false, stream);
    run_block<16, 32,  2>(wb[1], wsp[1], gm[1], bt[1], nbrP, phi, Wsw1, sums, pre, false, stream);
    run_block<32, 64,  2>(wb[2], wsp[2], gm[2], bt[2], nbrP, phi, Wsw2, sums, pre, false, stream);
    run_block<64, 64,  2>(wb[3], wsp[3], gm[3], bt[3], nbrP, phi, Wsw3, sums, pre, false, stream);
    run_block<64, 128, 2>(wb[4], wsp[4], gm[4], bt[4], nbrP, phi, Wsw4, sums, pre, true,  stream);

    // ---- dense output
    k_dense<<<(OUT_ELEMS+255)/256, 256, 0, stream>>>(pre, gridP, (float*)d_out);
}

// Round 5
// 859.713 us; speedup vs baseline: 4.6491x; 1.2448x over previous
//
#include <hip/hip_runtime.h>

#define N_VOX 50000
#define BATCH 2
#define DD 8
#define HH 160
#define WW 160
#define PD 10
#define PH 162
#define PW 162
#define KK 27
#define NCELL (BATCH*DD*HH*WW)         // 409600 = 400*1024
#define GRID_ELEMS (BATCH*PD*PH*PW)    // 524880
#define OUT_ELEMS (BATCH*128*DD*HH*WW) // 52,428,800

typedef __attribute__((ext_vector_type(8))) short short8v;
typedef __attribute__((ext_vector_type(4))) float float4v;

__device__ inline unsigned short f2bf(float f) {
    unsigned u = __float_as_uint(f);
    u += 0x7FFFu + ((u >> 16) & 1u);
    return (unsigned short)(u >> 16);
}

// ============ spatial sort: occupancy flags -> prefix sum -> permutation ====
__global__ void k_flags(const int* __restrict__ coors, int* __restrict__ flags) {
    int n = blockIdx.x * 256 + threadIdx.x;
    if (n >= N_VOX) return;
    int b = coors[n*4+0], z = coors[n*4+1], y = coors[n*4+2], x = coors[n*4+3];
    flags[((b*DD + z)*HH + y)*WW + x] = 1;
}

__global__ void k_scan1(const int* __restrict__ flags, int* __restrict__ scanout,
                        int* __restrict__ bsums) {
    __shared__ int s[256];
    int t = threadIdx.x, blk = blockIdx.x;
    int4 v = ((const int4*)(flags + blk*1024))[t];
    int tsum = v.x + v.y + v.z + v.w;
    s[t] = tsum; __syncthreads();
    for (int off = 1; off < 256; off <<= 1) {
        int x = (t >= off) ? s[t-off] : 0;
        __syncthreads(); s[t] += x; __syncthreads();
    }
    int excl = s[t] - tsum;
    int4 o; o.x = excl; o.y = excl + v.x; o.z = o.y + v.y; o.w = o.z + v.z;
    ((int4*)(scanout + blk*1024))[t] = o;
    if (t == 255) bsums[blk] = s[255];
}

__global__ void k_scan2(int* __restrict__ bsums) {
    __shared__ int s[512];
    int t = threadIdx.x;
    int orig = (t < 400) ? bsums[t] : 0;
    s[t] = orig; __syncthreads();
    for (int off = 1; off < 512; off <<= 1) {
        int x = (t >= off) ? s[t-off] : 0;
        __syncthreads(); s[t] += x; __syncthreads();
    }
    if (t < 400) bsums[t] = s[t] - orig;
}

__global__ void k_pos(const int* __restrict__ coors, const int* __restrict__ scanout,
                      const int* __restrict__ bsums, int* __restrict__ pos_of,
                      int* __restrict__ vox_at) {
    int n = blockIdx.x * 256 + threadIdx.x;
    if (n >= N_VOX) return;
    int b = coors[n*4+0], z = coors[n*4+1], y = coors[n*4+2], x = coors[n*4+3];
    int lin = ((b*DD + z)*HH + y)*WW + x;
    int pos = scanout[lin] + bsums[lin >> 10];
    pos_of[n] = pos;
    vox_at[pos] = n;
}

__global__ void k_gridP(const int* __restrict__ coors, const int* __restrict__ pos_of,
                        int* __restrict__ gridP) {
    int n = blockIdx.x * 256 + threadIdx.x;
    if (n >= N_VOX) return;
    int b = coors[n*4+0], z = coors[n*4+1], y = coors[n*4+2], x = coors[n*4+3];
    gridP[((b*PD + z+1)*PH + (y+1))*PW + (x+1)] = pos_of[n];
}

// iterate permuted index -> coalesced nbrP writes
__global__ void k_nbrP(const int* __restrict__ coors, const int* __restrict__ vox_at,
                       const int* __restrict__ gridP, int* __restrict__ nbrP) {
    int i = blockIdx.x * 256 + threadIdx.x;
    if (i >= N_VOX) return;
    int n = vox_at[i];
    int b = coors[n*4+0], z = coors[n*4+1]+1, y = coors[n*4+2]+1, x = coors[n*4+3]+1;
    int k = 0;
    for (int dz = -1; dz <= 1; ++dz)
        for (int dy = -1; dy <= 1; ++dy)
            for (int dx = -1; dx <= 1; ++dx) {
                int g = gridP[((b*PD + z+dz)*PH + (y+dy))*PW + (x+dx)];
                nbrP[k*N_VOX + i] = (g >= 0) ? g : N_VOX;
                ++k;
            }
}

// ============ phi: [N_VOX+1][4*CIN] bf16 (permuted rows); pad row = phi(0) ==
__global__ void k_phi0(const float* __restrict__ vf, const int* __restrict__ vox_at,
                       unsigned short* __restrict__ phi) {
    int e = blockIdx.x * 256 + threadIdx.x;
    if (e >= (N_VOX + 1) * 16) return;
    int i = e / 16, c = e % 16;
    float x = 0.f;
    if (i < N_VOX) x = vf[(size_t)vox_at[i] * 16 + c];
    float sig = 1.f / (1.f + __expf(-x));
    ushort4 p;
    p.x = f2bf(x * sig);
    p.y = f2bf(__expf(-(x + 1.f) * (x + 1.f)));
    p.z = f2bf(__expf(-x * x));
    p.w = f2bf(__expf(-(x - 1.f) * (x - 1.f)));
    *(ushort4*)&phi[(size_t)e * 4] = p;
}

// ============ all 5 layers' weight swizzle in ONE dispatch ============
// Wsw layout per layer: [kb][o][8] bf16, kb = global K / 8
struct WswzArgs {
    const float* wb[5];
    const float* ws[5];
    unsigned short* dst[5];
};
__global__ void k_wswz_all(WswzArgs a) {
    // per-layer elem counts: 27*CIN4*COUT
    constexpr int off[6]   = {0, 27648, 82944, 304128, 746496, 1631232};
    constexpr int lgCI4[5] = {6, 6, 7, 8, 8};
    constexpr int lgCO[5]  = {4, 5, 6, 6, 7};
    int e = blockIdx.x * 256 + threadIdx.x;
    if (e >= off[5]) return;
    int L = 0;
    #pragma unroll
    for (int i = 1; i < 5; ++i) L += (e >= off[i]);
    int el = e - off[L];
    int CIN4 = 1 << lgCI4[L], COUT = 1 << lgCO[L], CIN = CIN4 >> 2;
    int j8   = el & 7;
    int rest = el >> 3;
    int o    = rest & (COUT - 1);
    int kb   = rest >> lgCO[L];
    int kabs = kb * 8 + j8;
    int k  = kabs >> lgCI4[L];
    int c4 = kabs & (CIN4 - 1);
    int c = c4 >> 2, jj = c4 & 3;
    float v = (jj == 0) ? a.wb[L][(k * CIN + c) * COUT + o]
                        : a.ws[L][((k * CIN + c) * 3 + (jj - 1)) * COUT + o];
    a.dst[L][el] = f2bf(v);
}

// ============ MFMA conv: LDS-dbuf B (1 barrier/stage) + reg-pipelined A =====
// Block (mb,h): 128 voxel rows x COUTH cols. Fused BN-stats epilogue into
// 8 contention-striped accumulator copies (stride 256 floats each).
template<int CIN, int COUT, int NSPL>
__global__ __launch_bounds__(256, (COUT >= 128 ? 3 : 4)) void k_conv_mfma(
    const unsigned short* __restrict__ phi,   // [(N_VOX+1), 4*CIN] bf16
    const int*            __restrict__ nbrP,  // [KK, N_VOX] permuted, pad = N_VOX
    const unsigned short* __restrict__ Wsw,   // [Ktot/8, COUT, 8] bf16
    float*                __restrict__ pre,   // [N_VOX, COUT]
    float*                __restrict__ sums)  // [8][256] per-layer stats copies
{
    constexpr int CIN4   = CIN * 4;
    constexpr int BK     = 64;
    constexpr int SPK    = CIN4 / BK;          // 1,1,2,4,4
    constexpr int NSTAGE = KK * SPK;
    constexpr int COUTH  = COUT / NSPL;
    constexpr int NFW    = COUTH / 16;
    constexpr int NMB    = (N_VOX + 127) / 128;
    constexpr int NBLK   = NMB * NSPL;
    constexpr int PERX   = (NBLK + 7) / 8;
    constexpr int NCH4   = 8 * COUTH;          // uint4 chunks per stage-half
    constexpr int NLD    = (NCH4 + 255) / 256;

    __shared__ short Bs[2][BK * COUTH];

    int lb = blockIdx.x;
    int linear = (lb & 7) * PERX + (lb >> 3);  // XCD swizzle
    if (linear >= NBLK) return;
    const int mb = linear / NSPL, h = linear % NSPL;

    const int t = threadIdx.x, lane = t & 63, wv = t >> 6;
    const int l15 = lane & 15, q = lane >> 4;
    const int base = mb * 128;
    const int vg0 = base + wv * 32 + l15, vg1 = vg0 + 16;
    const int ob = h * COUTH;

    uint4 breg[NLD];
    auto stage_load = [&](int s) {
        const uint4* src = (const uint4*)Wsw + (size_t)s * 8 * COUT + ob;
        #pragma unroll
        for (int i = 0; i < NLD; ++i) {
            int c = t + i * 256;
            if ((NCH4 % 256 == 0) || c < NCH4) {
                int kbl = c / COUTH, oo = c % COUTH;   // constexpr pow2
                breg[i] = src[kbl * COUT + oo];
            }
        }
    };
    auto stage_write = [&](int buf) {
        uint4* dst = (uint4*)&Bs[buf][0];
        #pragma unroll
        for (int i = 0; i < NLD; ++i) {
            int c = t + i * 256;
            if ((NCH4 % 256 == 0) || c < NCH4) dst[c] = breg[i];
        }
    };

    // --- pipeline init: B stage 0, A frags for k=0, rows for k=1
    stage_load(0);
    int rows[2], rowsN[2];
    short8v A[2][2], An[2][2];
    rows[0]  = (vg0 < N_VOX) ? nbrP[vg0] : N_VOX;
    rows[1]  = (vg1 < N_VOX) ? nbrP[vg1] : N_VOX;
    rowsN[0] = (vg0 < N_VOX) ? nbrP[N_VOX + vg0] : N_VOX;
    rowsN[1] = (vg1 < N_VOX) ? nbrP[N_VOX + vg1] : N_VOX;
    {
        const unsigned short* p0 = phi + (size_t)rows[0] * CIN4 + q * 8;
        const unsigned short* p1 = phi + (size_t)rows[1] * CIN4 + q * 8;
        A[0][0] = *(const short8v*)p0;        A[0][1] = *(const short8v*)p1;
        A[1][0] = *(const short8v*)(p0 + 32); A[1][1] = *(const short8v*)(p1 + 32);
    }
    stage_write(0);
    __syncthreads();

    float4v acc[2][NFW];
    #pragma unroll
    for (int mi = 0; mi < 2; ++mi)
        #pragma unroll
        for (int nf = 0; nf < NFW; ++nf)
            acc[mi][nf] = (float4v){0.f, 0.f, 0.f, 0.f};

    for (int s = 0; s < NSTAGE; ++s) {
        if (s + 1 < NSTAGE) {
            stage_load(s + 1);                       // next B: global -> reg
            const int sp = s + 1;
            const int c4n = (sp % SPK) * BK;
            if (sp % SPK == 0) { rows[0] = rowsN[0]; rows[1] = rowsN[1]; }
            const unsigned short* p0 = phi + (size_t)rows[0] * CIN4 + c4n + q * 8;
            const unsigned short* p1 = phi + (size_t)rows[1] * CIN4 + c4n + q * 8;
            An[0][0] = *(const short8v*)p0;        An[0][1] = *(const short8v*)p1;
            An[1][0] = *(const short8v*)(p0 + 32); An[1][1] = *(const short8v*)(p1 + 32);
            if (sp % SPK == 0) {
                int k2 = sp / SPK + 1;
                if (k2 < KK) {
                    rowsN[0] = (vg0 < N_VOX) ? nbrP[k2 * N_VOX + vg0] : N_VOX;
                    rowsN[1] = (vg1 < N_VOX) ? nbrP[k2 * N_VOX + vg1] : N_VOX;
                }
            }
        }
        const short* bb = &Bs[s & 1][0];
        #pragma unroll
        for (int kk = 0; kk < 2; ++kk) {
            #pragma unroll
            for (int nf = 0; nf < NFW; ++nf) {
                short8v bfr = *(const short8v*)(bb + ((kk * 4 + q) * COUTH + nf * 16 + l15) * 8);
                acc[0][nf] = __builtin_amdgcn_mfma_f32_16x16x32_bf16(A[kk][0], bfr, acc[0][nf], 0, 0, 0);
                acc[1][nf] = __builtin_amdgcn_mfma_f32_16x16x32_bf16(A[kk][1], bfr, acc[1][nf], 0, 0, 0);
            }
        }
        if (s + 1 < NSTAGE) stage_write((s + 1) & 1);  // other buffer: pre-barrier safe
        __syncthreads();
        #pragma unroll
        for (int kk = 0; kk < 2; ++kk) { A[kk][0] = An[kk][0]; A[kk][1] = An[kk][1]; }
    }

    // --- store (C/D layout: col=lane&15, row=(lane>>4)*4+r  [measured m89])
    #pragma unroll
    for (int mi = 0; mi < 2; ++mi)
        #pragma unroll
        for (int nf = 0; nf < NFW; ++nf)
            #pragma unroll
            for (int r = 0; r < 4; ++r) {
                int v = base + wv * 32 + mi * 16 + q * 4 + r;
                if (v < N_VOX)
                    pre[(size_t)v * COUT + ob + nf * 16 + l15] = acc[mi][nf][r];
            }

    // --- fused BN stats: per-col sum/sumsq over this block's valid rows
    float* S = sums + (blockIdx.x & 7) * 256;
    #pragma unroll
    for (int nf = 0; nf < NFW; ++nf) {
        float s1 = 0.f, s2 = 0.f;
        #pragma unroll
        for (int mi = 0; mi < 2; ++mi)
            #pragma unroll
            for (int r = 0; r < 4; ++r) {
                int v = base + wv * 32 + mi * 16 + q * 4 + r;
                if (v < N_VOX) {
                    float a = acc[mi][nf][r];
                    s1 += a; s2 += a * a;
                }
            }
        s1 += __shfl_xor(s1, 16); s1 += __shfl_xor(s1, 32);
        s2 += __shfl_xor(s2, 16); s2 += __shfl_xor(s2, 32);
        if (q == 0) {
            atomicAdd(&S[ob + nf * 16 + l15], s1);
            atomicAdd(&S[COUT + ob + nf * 16 + l15], s2);
        }
    }
}

// ============ BN apply (reads 8 stat copies) fused with next-layer phi ======
template<int COUT>
__global__ void k_bnapply_phi(const float* __restrict__ pre, const float* __restrict__ sums,
                              const float* __restrict__ gm, const float* __restrict__ bt,
                              unsigned short* __restrict__ phi) {
    int e = blockIdx.x*256 + threadIdx.x;
    if (e >= (N_VOX + 1) * COUT) return;
    int i = e / COUT, c = e % COUT;
    float x = 0.f;
    if (i < N_VOX) {
        float s1 = 0.f, s2 = 0.f;
        #pragma unroll
        for (int xo = 0; xo < 8; ++xo) {
            s1 += sums[xo * 256 + c];
            s2 += sums[xo * 256 + COUT + c];
        }
        float mu  = s1 * (1.f / N_VOX);
        float var = s2 * (1.f / N_VOX) - mu*mu;
        float v = (pre[(size_t)i*COUT + c] - mu) * rsqrtf(var + 1e-3f) * gm[c] + bt[c];
        x = fmaxf(v, 0.f);
    }
    float sig = 1.f / (1.f + __expf(-x));
    ushort4 p;
    p.x = f2bf(x * sig);
    p.y = f2bf(__expf(-(x + 1.f) * (x + 1.f)));
    p.z = f2bf(__expf(-x * x));
    p.w = f2bf(__expf(-(x - 1.f) * (x - 1.f)));
    *(ushort4*)&phi[(size_t)e * 4] = p;
}

template<int COUT>
__global__ void k_bnapply_f32(float* __restrict__ pre, const float* __restrict__ sums,
                              const float* __restrict__ gm, const float* __restrict__ bt) {
    int e = blockIdx.x*256 + threadIdx.x;
    if (e >= N_VOX*COUT) return;
    int c = e % COUT;
    float s1 = 0.f, s2 = 0.f;
    #pragma unroll
    for (int xo = 0; xo < 8; ++xo) {
        s1 += sums[xo * 256 + c];
        s2 += sums[xo * 256 + COUT + c];
    }
    float mu  = s1 * (1.f / N_VOX);
    float var = s2 * (1.f / N_VOX) - mu*mu;
    float x = (pre[e] - mu) * rsqrtf(var + 1e-3f) * gm[c] + bt[c];
    pre[e] = fmaxf(x, 0.f);
}

// ============ dense fill, float4 writes: out[b][c*8+z][y][x] ================
__global__ void k_dense(const float* __restrict__ feat, const int* __restrict__ gridP,
                        float* __restrict__ out) {
    int e4 = blockIdx.x*256 + threadIdx.x;
    if (e4 >= OUT_ELEMS/4) return;
    int e = e4 * 4;
    int x  = e % WW;                      // multiple of 4
    int y  = (e / WW) % HH;
    int cz = (e / (WW*HH)) % (128*DD);
    int b  = e / (WW*HH*128*DD);
    int c = cz >> 3, z = cz & 7;
    const int* gp = &gridP[((b*PD + z+1)*PH + (y+1))*PW + (x+1)];
    int g0 = gp[0], g1 = gp[1], g2 = gp[2], g3 = gp[3];
    float4 o;
    o.x = (g0 >= 0) ? feat[(size_t)g0*128 + c] : 0.f;
    o.y = (g1 >= 0) ? feat[(size_t)g1*128 + c] : 0.f;
    o.z = (g2 >= 0) ? feat[(size_t)g2*128 + c] : 0.f;
    o.w = (g3 >= 0) ? feat[(size_t)g3*128 + c] : 0.f;
    *(float4*)&out[e] = o;
}

// ============ host side ============
template<int CIN, int COUT, int NSPL>
static void run_block(const float* gm, const float* bt,
                      const int* nbrP, unsigned short* phi, const unsigned short* Wsw,
                      float* sums, float* pre, bool last, hipStream_t stream) {
    constexpr int NMB  = (N_VOX + 127) / 128;
    constexpr int NBLK = NMB * NSPL;
    constexpr int GRID = ((NBLK + 7) / 8) * 8;
    k_conv_mfma<CIN, COUT, NSPL><<<GRID, 256, 0, stream>>>(phi, nbrP, Wsw, pre, sums);
    if (last) {
        k_bnapply_f32<COUT><<<(N_VOX * COUT + 255) / 256, 256, 0, stream>>>(pre, sums, gm, bt);
    } else {
        int n = (N_VOX + 1) * COUT;
        k_bnapply_phi<COUT><<<(n + 255) / 256, 256, 0, stream>>>(pre, sums, gm, bt, phi);
    }
}

extern "C" void kernel_launch(void* const* d_in, const int* in_sizes, int n_in,
                              void* d_out, int out_size, void* d_ws, size_t ws_size,
                              hipStream_t stream) {
    const float* vf    = (const float*)d_in[0];
    const int*   coors = (const int*)d_in[1];
    const float* wb[5] = {(const float*)d_in[3],  (const float*)d_in[7],
                          (const float*)d_in[11], (const float*)d_in[15],
                          (const float*)d_in[19]};
    const float* wsp[5]= {(const float*)d_in[4],  (const float*)d_in[8],
                          (const float*)d_in[12], (const float*)d_in[16],
                          (const float*)d_in[20]};
    const float* gm[5] = {(const float*)d_in[5],  (const float*)d_in[9],
                          (const float*)d_in[13], (const float*)d_in[17],
                          (const float*)d_in[21]};
    const float* bt[5] = {(const float*)d_in[6],  (const float*)d_in[10],
                          (const float*)d_in[14], (const float*)d_in[18],
                          (const float*)d_in[22]};

    // workspace bump allocator (256B aligned), ~66 MB total
    char* p = (char*)d_ws;
    auto alloc = [&](size_t bytes) {
        char* r = p;
        p += (bytes + 255) & ~(size_t)255;
        return r;
    };
    int*            flags   = (int*)           alloc((size_t)NCELL * 4);
    int*            scanout = (int*)           alloc((size_t)NCELL * 4);
    int*            bsums   = (int*)           alloc(512 * 4);
    int*            pos_of  = (int*)           alloc((size_t)N_VOX * 4);
    int*            vox_at  = (int*)           alloc((size_t)N_VOX * 4);
    int*            gridP   = (int*)           alloc((size_t)GRID_ELEMS * 4);
    int*            nbrP    = (int*)           alloc((size_t)KK * N_VOX * 4);
    unsigned short* Wsw0    = (unsigned short*)alloc((size_t)KK * 64  * 16  * 2);
    unsigned short* Wsw1    = (unsigned short*)alloc((size_t)KK * 64  * 32  * 2);
    unsigned short* Wsw2    = (unsigned short*)alloc((size_t)KK * 128 * 64  * 2);
    unsigned short* Wsw3    = (unsigned short*)alloc((size_t)KK * 256 * 64  * 2);
    unsigned short* Wsw4    = (unsigned short*)alloc((size_t)KK * 256 * 128 * 2);
    unsigned short* phi     = (unsigned short*)alloc((size_t)(N_VOX + 1) * 256 * 2);
    float*          sumsAll = (float*)         alloc(5 * 8 * 256 * 4);
    float*          pre     = (float*)         alloc((size_t)N_VOX * 128 * 4);

    // ---- zero init (re-poisoned to 0xAA before every timed call)
    hipMemsetAsync(flags, 0, (size_t)NCELL * 4, stream);
    hipMemsetAsync(gridP, 0xFF, (size_t)GRID_ELEMS * 4, stream);
    hipMemsetAsync(sumsAll, 0, 5 * 8 * 256 * 4, stream);

    // ---- all weight swizzles in one dispatch (independent of activations)
    WswzArgs wa;
    for (int i = 0; i < 5; ++i) { wa.wb[i] = wb[i]; wa.ws[i] = wsp[i]; }
    wa.dst[0] = Wsw0; wa.dst[1] = Wsw1; wa.dst[2] = Wsw2; wa.dst[3] = Wsw3; wa.dst[4] = Wsw4;
    k_wswz_all<<<(1631232 + 255) / 256, 256, 0, stream>>>(wa);

    // ---- spatial permutation + rulebook
    k_flags<<<(N_VOX+255)/256, 256, 0, stream>>>(coors, flags);
    k_scan1<<<NCELL/1024, 256, 0, stream>>>(flags, scanout, bsums);
    k_scan2<<<1, 512, 0, stream>>>(bsums);
    k_pos  <<<(N_VOX+255)/256, 256, 0, stream>>>(coors, scanout, bsums, pos_of, vox_at);
    k_gridP<<<(N_VOX+255)/256, 256, 0, stream>>>(coors, pos_of, gridP);
    k_nbrP <<<(N_VOX+255)/256, 256, 0, stream>>>(coors, vox_at, gridP, nbrP);
    {
        int n = (N_VOX + 1) * 16;
        k_phi0<<<(n + 255) / 256, 256, 0, stream>>>(vf, vox_at, phi);
    }

    // ---- 5 KAN blocks (per-layer stats slice; phi overwritten in stream order)
    run_block<16, 16,  1>(gm[0], bt[0], nbrP, phi, Wsw0, sumsAll + 0*2048, pre, false, stream);
    run_block<16, 32,  2>(gm[1], bt[1], nbrP, phi, Wsw1, sumsAll + 1*2048, pre, false, stream);
    run_block<32, 64,  2>(gm[2], bt[2], nbrP, phi, Wsw2, sumsAll + 2*2048, pre, false, stream);
    run_block<64, 64,  2>(gm[3], bt[3], nbrP, phi, Wsw3, sumsAll + 3*2048, pre, false, stream);
    run_block<64, 128, 2>(gm[4], bt[4], nbrP, phi, Wsw4, sumsAll + 4*2048, pre, true,  stream);

    // ---- dense output
    k_dense<<<(OUT_ELEMS/4 + 255)/256, 256, 0, stream>>>(pre, gridP, (float*)d_out);
}